// Round 11
// baseline (82.463 us; speedup 1.0000x reference)
//
#include <hip/hip_runtime.h>

#define NN 512
#define NB 256
#define XMAGIC 0x7E31C9A5u
#define FMAGIC 0x5AD0F1A6u

// ---------------- single kernel: partner-paired dot + rows + atomic tail -----
// 256 blocks x 512 threads. Blocks b and b^1 pair up: each loads the pair's
// FOUR anchor rows (4q..4q+3, registers; launch_bounds(512,2) -> 256-VGPR
// budget, no remat -- r5's failure mode) and dots them against only ITS
// 256-row half of P => 512 KB/CU global reads, HALF of every prior round.
// (r4/r6/r8/r10 showed the dot sits at a ~50 GB/s/CU pure-L2-fill roofline;
// bytes are the only lever left.) Partners swap the 2x256 partials they
// computed for each other via relaxed agent-scope atomics (r4-proven
// transport), assemble srow[2][512] bitwise-identically (same 512-dim chain,
// slots g+16c, xor tree 1/2/4/8 per (i,k)), then run the r10-verified
// concurrent rows phase and the r4-proven atomic tail.
__global__ __launch_bounds__(512, 2) void sap_fused(const float* __restrict__ P,
                                                    const int* __restrict__ labels,
                                                    unsigned* __restrict__ xch,
                                                    unsigned* __restrict__ xflags,
                                                    unsigned* __restrict__ pa_bits,
                                                    unsigned* __restrict__ pflags,
                                                    float* __restrict__ out) {
    __shared__ float part[4][256];     // union-anchor partials over my k-half
    __shared__ float srow[2][NN];
    __shared__ int   labels_sh[NN];
    __shared__ float posf2[2][NN];
    __shared__ int   poslist2[2][NN];
    __shared__ int   npos2[2];
    __shared__ float wave_part2[2][4];
    __shared__ float pa_out[2];
    __shared__ float sh[256];

    const int t    = threadIdx.x;      // 0..511
    const int lane = t & 63;
    const int wave = t >> 6;           // 0..7
    const int g    = lane & 15;        // lane within 16-group
    const int grp  = lane >> 4;        // 0..3: row-group within wave
    const int b    = blockIdx.x;
    const int p    = b ^ 1;            // partner block
    const int q    = b >> 1;           // pair id
    const int i0   = b * 2;            // my anchors: 2b, 2b+1
    const int half = b & 1;            // my k-half
    const int H0   = half * 256;       // my k-half start

    if (t < 128) ((int4*)labels_sh)[t] = ((const int4*)labels)[t];

    // ---- the pair's 4 anchor rows (4q..4q+3) into regs, slots {g+16c}
    float4 a0[8], a1[8], a2[8], a3[8];
    {
        const float4* A0 = (const float4*)&P[(4 * q + 0) * NN];
        const float4* A1 = (const float4*)&P[(4 * q + 1) * NN];
        const float4* A2 = (const float4*)&P[(4 * q + 2) * NN];
        const float4* A3 = (const float4*)&P[(4 * q + 3) * NN];
#pragma unroll
        for (int c = 0; c < 8; ++c) {
            a0[c] = A0[g + 16 * c];
            a1[c] = A1[g + 16 * c];
            a2[c] = A2[g + 16 * c];
            a3[c] = A3[g + 16 * c];
        }
    }

    // ---- dot phase: only MY 256-row half; wave w owns rows H0+[32w,32w+32)
#pragma unroll 2
    for (int bb_ = 0; bb_ < 8; ++bb_) {
        const int k = H0 + wave * 32 + bb_ * 4 + grp;
        const float4* B = (const float4*)&P[k * NN];
        float s0 = 0.f, s1 = 0.f, s2 = 0.f, s3 = 0.f;
#pragma unroll
        for (int c = 0; c < 8; ++c) {
            const float4 bb = B[g + 16 * c];
            s0 += a0[c].x * bb.x; s0 += a0[c].y * bb.y;
            s0 += a0[c].z * bb.z; s0 += a0[c].w * bb.w;
            s1 += a1[c].x * bb.x; s1 += a1[c].y * bb.y;
            s1 += a1[c].z * bb.z; s1 += a1[c].w * bb.w;
            s2 += a2[c].x * bb.x; s2 += a2[c].y * bb.y;
            s2 += a2[c].z * bb.z; s2 += a2[c].w * bb.w;
            s3 += a3[c].x * bb.x; s3 += a3[c].y * bb.y;
            s3 += a3[c].z * bb.z; s3 += a3[c].w * bb.w;
        }
#pragma unroll
        for (int off = 1; off < 16; off <<= 1) {   // within the 16-group
            s0 += __shfl_xor(s0, off);
            s1 += __shfl_xor(s1, off);
            s2 += __shfl_xor(s2, off);
            s3 += __shfl_xor(s3, off);
        }
        if (g == 0) {
            const int kk = k - H0;
            part[0][kk] = s0; part[1][kk] = s1;
            part[2][kk] = s2; part[3][kk] = s3;
        }
    }
    __syncthreads();

    // ---- publish the partner-owned partials (unions 2*(1-half)+{0,1}): 512 f
    {
        const int up0 = 2 * (1 - half);
        const int m   = t >> 8;        // 0..1 (partner's local anchor index)
        const int kk  = t & 255;
        __hip_atomic_store(&xch[(size_t)b * 512 + m * 256 + kk],
                           __float_as_uint(part[up0 + m][kk]),
                           __ATOMIC_RELAXED, __HIP_MEMORY_SCOPE_AGENT);
        asm volatile("s_waitcnt vmcnt(0)" ::: "memory");
        __syncthreads();               // all 512 stores drained
        if (t == 0)
            __hip_atomic_store(&xflags[b], XMAGIC,
                               __ATOMIC_RELAXED, __HIP_MEMORY_SCOPE_AGENT);
    }

    // ---- wait for partner's flag, assemble full srow[2][512]
    if (t == 0) {
        while (__hip_atomic_load(&xflags[p], __ATOMIC_RELAXED,
                                 __HIP_MEMORY_SCOPE_AGENT) != XMAGIC)
            __builtin_amdgcn_s_sleep(2);
    }
    __syncthreads();
    {
        const int um0 = 2 * half;      // my union indices
        const int Hp0 = (1 - half) * 256;
#pragma unroll
        for (int m = 0; m < 2; ++m) {
            if (t >= H0 && t < H0 + 256) {
                srow[m][t] = part[um0 + m][t - H0];
            } else {
                srow[m][t] = __uint_as_float(
                    __hip_atomic_load(&xch[(size_t)p * 512 + m * 256 + (t - Hp0)],
                                      __ATOMIC_RELAXED, __HIP_MEMORY_SCOPE_AGENT));
            }
        }
    }

    // ---- rows phase: both anchors concurrently (r10-verified structure)
    const float C1   = 100.0f * 1.44269504088896340736f;
    const float CLIP = 50.0f  * 1.44269504088896340736f;
    const int a  = wave >> 2;          // which anchor this wave serves
    const int w4 = wave & 3;           // wave index within the anchor's 4

    __syncthreads();                   // srow ready
    if (t == 0) { npos2[0] = 0; npos2[1] = 0; }
    if (t < 8) wave_part2[t >> 2][t & 3] = 0.f;
    __syncthreads();
#pragma unroll
    for (int aa = 0; aa < 2; ++aa) {
        const int i  = i0 + aa;
        const int li = labels_sh[i];
        bool pp = (labels_sh[t] == li) && (t != i);
        posf2[aa][t] = pp ? 1.f : 0.f;
        if (pp) { int idx = atomicAdd(&npos2[aa], 1); poslist2[aa][idx] = t; }
    }
    __syncthreads();

    {
        const int   i   = i0 + a;
        const int   cnt = npos2[a];    // positives excluding self
        float acc = 0.f;               // lane-0 accumulation per wave
        if (cnt > 0) {
            const float* sr = srow[a];
            const float* pf = posf2[a];
            const int*   pl = poslist2[a];
            for (int idx = w4; idx <= cnt; idx += 4) {  // idx==cnt -> j==i
                const int   j   = (idx == cnt) ? i : pl[idx];
                const float sij = sr[j];
                float sum_all = 0.f, sum_pos = 0.f;
#pragma unroll
                for (int kk = 0; kk < 8; kk++) {
                    const int k = lane + (kk << 6);
                    float y = (sij - sr[k]) * C1;
                    y = fminf(fmaxf(y, -CLIP), CLIP);
                    float tt = 1.0f / (1.0f + exp2f(y));
                    if (k == j) tt = 0.f;      // (1-eye)[j,k] factor
                    sum_all += tt;
                    sum_pos += tt * pf[k];     // pf[i]==0 excludes k==i
                }
#pragma unroll
                for (int off = 32; off; off >>= 1) {
                    sum_all += __shfl_down(sum_all, off);
                    sum_pos += __shfl_down(sum_pos, off);
                }
                if (lane == 0) {
                    const float den = 1.0f + sum_all;
                    acc += ((j == i) ? 1.0f : (1.0f + sum_pos)) / den;
                }
            }
        }
        if (lane == 0) wave_part2[a][w4] = acc;
    }
    __syncthreads();
    if (t == 0) {
#pragma unroll
        for (int aa = 0; aa < 2; ++aa) {
            const int cnt2 = npos2[aa];
            if (cnt2 == 0) { pa_out[aa] = 0.f; continue; }
            float tot = wave_part2[aa][0] + wave_part2[aa][1]
                      + wave_part2[aa][2] + wave_part2[aa][3];
            pa_out[aa] = tot / (float)(cnt2 + 1);
        }
    }
    __syncthreads();

    // ---- publish this block's two per_anchor values + flag (relaxed atomics)
    if (t == 0) {
        __hip_atomic_store(&pa_bits[i0],     __float_as_uint(pa_out[0]),
                           __ATOMIC_RELAXED, __HIP_MEMORY_SCOPE_AGENT);
        __hip_atomic_store(&pa_bits[i0 + 1], __float_as_uint(pa_out[1]),
                           __ATOMIC_RELAXED, __HIP_MEMORY_SCOPE_AGENT);
        asm volatile("s_waitcnt vmcnt(0)" ::: "memory");
        __hip_atomic_store(&pflags[b], FMAGIC,
                           __ATOMIC_RELAXED, __HIP_MEMORY_SCOPE_AGENT);
    }

    if (b != 0) return;                // finisher is block 0

    // ---- block 0: wait for all flags (relaxed polls -> no L2 inv storm)
    if (t < NB) {
        while (__hip_atomic_load(&pflags[t], __ATOMIC_RELAXED,
                                 __HIP_MEMORY_SCOPE_AGENT) != FMAGIC)
            __builtin_amdgcn_s_sleep(8);
        // reset ALL flags for replay-robustness (0 != magic)
        __hip_atomic_store(&pflags[t], 0u, __ATOMIC_RELAXED,
                           __HIP_MEMORY_SCOPE_AGENT);
        __hip_atomic_store(&xflags[t], 0u, __ATOMIC_RELAXED,
                           __HIP_MEMORY_SCOPE_AGENT);
    }
    __syncthreads();

    // ---- final reduce (bitwise-identical round-0 tree)
    if (t < 256) {
        float v0 = __uint_as_float(__hip_atomic_load(&pa_bits[t], __ATOMIC_RELAXED,
                                                     __HIP_MEMORY_SCOPE_AGENT));
        float v1 = __uint_as_float(__hip_atomic_load(&pa_bits[t + 256], __ATOMIC_RELAXED,
                                                     __HIP_MEMORY_SCOPE_AGENT));
        sh[t] = v0 + v1;
    }
    __syncthreads();
    for (int s = 128; s; s >>= 1) {
        if (t < s) sh[t] += sh[t + s];
        __syncthreads();
    }
    if (t == 0) out[0] = 1.0f - sh[0] / (float)NN;
}

extern "C" void kernel_launch(void* const* d_in, const int* in_sizes, int n_in,
                              void* d_out, int out_size, void* d_ws, size_t ws_size,
                              hipStream_t stream) {
    const float* preds  = (const float*)d_in[0];
    const int*   labels = (const int*)d_in[1];
    float* out = (float*)d_out;

    unsigned* xch     = (unsigned*)d_ws;           // 256*512 u32 = 512 KB
    unsigned* xflags  = xch + NB * 512;            // 256 u32
    unsigned* pa_bits = xflags + NB;               // 512 u32
    unsigned* pflags  = pa_bits + NN;              // 256 u32

    sap_fused<<<NB, 512, 0, stream>>>(preds, labels, xch, xflags,
                                      pa_bits, pflags, out);
}

// Round 12
// 78.614 us; speedup vs baseline: 1.0490x; 1.0490x over previous
//
#include <hip/hip_runtime.h>

#define NN 512
#define NB 256                 // 256 blocks x 2 anchors each
#define FMAGIC 0x5AD0F1A6u

// ---------------- single kernel: async-staged dot + rows + atomic tail -------
// 256 blocks x 512 threads, 2 anchors per block (i = 2b, 2b+1).
// r5/r6/r8/r10/r11 scorecard -> dot phase is bound by the per-CU VMEM
// demand-load path (~50 GB/s/CU, MSHR-limited: occupancy null, order null,
// bytes scale it). Fix: route B-rows through global_load_lds (async DMA to
// LDS, bypasses the VGPR/demand-miss round-trip). Each wave double-buffers
// its OWN 4-row batch chunk (no barriers; per-wave counted vmcnt(8): batch
// n+1 stages while batch n computes). Dot reads the same values in the same
// slot order (g+16c, xor tree 1/2/4/8) -> srow bitwise-identical to r4.
// Rows phase and relaxed-atomic tail: r4 verbatim.
__global__ __launch_bounds__(512) void sap_fused(const float* __restrict__ P,
                                                 const int* __restrict__ labels,
                                                 unsigned* __restrict__ pa_bits,
                                                 unsigned* __restrict__ flags,
                                                 float* __restrict__ out) {
    __shared__ float stage[8][2][2048];    // per-wave dbuf: 4 rows x 512 f
    __shared__ float arow[2][NN];
    __shared__ float srow[2][NN];
    __shared__ int   labels_sh[NN];
    __shared__ float posf[NN];
    __shared__ int   poslist[NN];
    __shared__ int   npos_cnt;
    __shared__ float wave_part[8];
    __shared__ float pa_out[2];
    __shared__ float sh[256];

    const int t    = threadIdx.x;          // 0..511
    const int lane = t & 63;
    const int wave = t >> 6;               // 0..7
    const int g    = lane & 15;            // lane within 16-group
    const int grp  = lane >> 4;            // 0..3: row-group within wave
    const int b    = blockIdx.x;
    const int i0   = b * 2;

    // ---- stage labels + both anchor rows into LDS (coalesced)
    if (t < 128) ((int4*)labels_sh)[t] = ((const int4*)labels)[t];
    if (t < 256) ((float4*)&arow[0][0])[t] = ((const float4*)&P[i0 * NN])[t];
    __syncthreads();                       // also drains vmcnt for every wave

    // ---- dot phase: wave w owns rows [64w, 64w+64); 16 batches of 4 rows.
    // Stage batch -> private LDS chunk via global_load_lds (8x 16B/lane instr),
    // double-buffered, vmcnt(8) keeps next batch in flight during compute.
    {
        const float4* A0 = (const float4*)&arow[0][0];
        const float4* A1 = (const float4*)&arow[1][0];

        auto stage_batch = [&](int n, int buf) {
            const int kbase = wave * 64 + n * 4;
#pragma unroll
            for (int j = 0; j < 8; ++j) {
                const int r = j >> 1, h = j & 1;
                const float* gp = &P[(kbase + r) * NN + h * 256 + lane * 4];
                float* lp = &stage[wave][buf][r * 512 + h * 256];
                __builtin_amdgcn_global_load_lds(
                    (const __attribute__((address_space(1))) void*)gp,
                    (__attribute__((address_space(3))) void*)lp, 16, 0, 0);
            }
        };
        auto dot_batch = [&](int n, int buf) {
            const int k0 = wave * 64 + n * 4;
            const float4* B = (const float4*)&stage[wave][buf][grp * 512];
            float s0 = 0.f, s1 = 0.f;
#pragma unroll
            for (int c = 0; c < 8; ++c) {
                const float4 bb = B[g + 16 * c];
                const float4 a0 = A0[g + 16 * c];
                const float4 a1 = A1[g + 16 * c];
                s0 += a0.x * bb.x; s0 += a0.y * bb.y;
                s0 += a0.z * bb.z; s0 += a0.w * bb.w;
                s1 += a1.x * bb.x; s1 += a1.y * bb.y;
                s1 += a1.z * bb.z; s1 += a1.w * bb.w;
            }
#pragma unroll
            for (int off = 1; off < 16; off <<= 1) {   // within the 16-group
                s0 += __shfl_xor(s0, off);
                s1 += __shfl_xor(s1, off);
            }
            if (g == 0) {
                const int k = k0 + grp;
                srow[0][k] = s0; srow[1][k] = s1;
            }
        };

        stage_batch(0, 0);
        for (int n = 0; n < 15; ++n) {
            stage_batch(n + 1, (n + 1) & 1);
            asm volatile("s_waitcnt vmcnt(8)" ::: "memory");  // batch n landed
            __builtin_amdgcn_sched_barrier(0);
            dot_batch(n, n & 1);
        }
        asm volatile("s_waitcnt vmcnt(0)" ::: "memory");      // last batch
        __builtin_amdgcn_sched_barrier(0);
        dot_batch(15, 1);
    }

    // ---- rows phase (verbatim round-4: serial 2 anchors, 8 waves stride-8)
    const float C1   = 100.0f * 1.44269504088896340736f;
    const float CLIP = 50.0f  * 1.44269504088896340736f;

    for (int a = 0; a < 2; ++a) {
        const int i = i0 + a;
        __syncthreads();                   // srow ready / protect reused buffers
        if (t == 0) npos_cnt = 0;
        if (t < 8) wave_part[t] = 0.f;
        __syncthreads();
        const int li = labels_sh[i];
        {
            bool p  = (labels_sh[t] == li) && (t != i);
            posf[t] = p ? 1.f : 0.f;
            if (p) { int idx = atomicAdd(&npos_cnt, 1); poslist[idx] = t; }
        }
        __syncthreads();

        const int cnt = npos_cnt;          // positives excluding self
        if (cnt == 0) {                    // n_pos == 1 -> per_anchor = 0
            if (t == 0) pa_out[a] = 0.f;
            continue;
        }

        const float* sr = srow[a];
        float acc = 0.f;                   // lane-0 accumulation per wave
        for (int idx = wave; idx <= cnt; idx += 8) {   // idx==cnt -> j==i (eye)
            const int   j   = (idx == cnt) ? i : poslist[idx];
            const float sij = sr[j];
            float sum_all = 0.f, sum_pos = 0.f;
#pragma unroll
            for (int kk = 0; kk < 8; kk++) {
                const int k = lane + (kk << 6);
                float y = (sij - sr[k]) * C1;
                y = fminf(fmaxf(y, -CLIP), CLIP);
                float tt = 1.0f / (1.0f + exp2f(y));
                if (k == j) tt = 0.f;      // (1-eye)[j,k] factor
                sum_all += tt;
                sum_pos += tt * posf[k];   // posf[i]==0 excludes k==i
            }
#pragma unroll
            for (int off = 32; off; off >>= 1) {
                sum_all += __shfl_down(sum_all, off);
                sum_pos += __shfl_down(sum_pos, off);
            }
            if (lane == 0) {
                const float den = 1.0f + sum_all;
                acc += ((j == i) ? 1.0f : (1.0f + sum_pos)) / den;
            }
        }
        if (lane == 0) wave_part[wave] = acc;
        __syncthreads();
        if (t == 0) {
            float tot = 0.f;
#pragma unroll
            for (int w = 0; w < 8; ++w) tot += wave_part[w];
            pa_out[a] = tot / (float)(cnt + 1);
        }
    }
    __syncthreads();

    // ---- publish this block's two per_anchor values + flag (relaxed atomics)
    if (t == 0) {
        __hip_atomic_store(&pa_bits[i0],     __float_as_uint(pa_out[0]),
                           __ATOMIC_RELAXED, __HIP_MEMORY_SCOPE_AGENT);
        __hip_atomic_store(&pa_bits[i0 + 1], __float_as_uint(pa_out[1]),
                           __ATOMIC_RELAXED, __HIP_MEMORY_SCOPE_AGENT);
        // order data-atomics before flag-atomic without any cache writeback:
        asm volatile("s_waitcnt vmcnt(0)" ::: "memory");
        __hip_atomic_store(&flags[b], FMAGIC,
                           __ATOMIC_RELAXED, __HIP_MEMORY_SCOPE_AGENT);
    }

    if (b != 0) return;                    // finisher is block 0

    // ---- block 0: wait for all flags (relaxed polls -> no L2 inv storm)
    if (t < NB) {
        while (__hip_atomic_load(&flags[t], __ATOMIC_RELAXED,
                                 __HIP_MEMORY_SCOPE_AGENT) != FMAGIC)
            __builtin_amdgcn_s_sleep(8);
        // reset for replay-robustness (0 != FMAGIC)
        __hip_atomic_store(&flags[t], 0u, __ATOMIC_RELAXED,
                           __HIP_MEMORY_SCOPE_AGENT);
    }
    __syncthreads();

    // ---- final reduce (bitwise-identical round-0 tree)
    if (t < 256) {
        float v0 = __uint_as_float(__hip_atomic_load(&pa_bits[t], __ATOMIC_RELAXED,
                                                     __HIP_MEMORY_SCOPE_AGENT));
        float v1 = __uint_as_float(__hip_atomic_load(&pa_bits[t + 256], __ATOMIC_RELAXED,
                                                     __HIP_MEMORY_SCOPE_AGENT));
        sh[t] = v0 + v1;
    }
    __syncthreads();
    for (int s = 128; s; s >>= 1) {
        if (t < s) sh[t] += sh[t + s];
        __syncthreads();
    }
    if (t == 0) out[0] = 1.0f - sh[0] / (float)NN;
}

extern "C" void kernel_launch(void* const* d_in, const int* in_sizes, int n_in,
                              void* d_out, int out_size, void* d_ws, size_t ws_size,
                              hipStream_t stream) {
    const float* preds  = (const float*)d_in[0];
    const int*   labels = (const int*)d_in[1];
    float* out = (float*)d_out;

    unsigned* pa_bits = (unsigned*)d_ws;           // 512 u32 (float bits)
    unsigned* flags   = pa_bits + NN;              // 256 u32

    sap_fused<<<NB, 512, 0, stream>>>(preds, labels, pa_bits, flags, out);
}